// Round 1
// baseline (145.421 us; speedup 1.0000x reference)
//
#include <hip/hip_runtime.h>
#include <math.h>

#define BB 8
#define TT 4095
#define DD 1024
#define NN 7
#define GG 585           // TT / NN
#define BN (BB * NN)     // 56
#define GSPLIT 8
#define GCHUNK 74        // ceil(585/8)

// ---------------------------------------------------------------------------
// Kernel 1: partial group-mean sums.  grid = (GSPLIT, BN), block = 256.
// nodes[b,n,d] = mean_g x[b, g*7+n, d]; here we compute per-gchunk partials.
// ---------------------------------------------------------------------------
__global__ __launch_bounds__(256) void k_mean_partial(
    const float* __restrict__ x, float* __restrict__ partial) {
    int gs = blockIdx.x;             // 0..7
    int bn = blockIdx.y;             // 0..55
    int b = bn / NN, n = bn % NN;
    int t4 = threadIdx.x;            // float4 index within row, 0..255
    int g0 = gs * GCHUNK;
    int g1 = g0 + GCHUNK; if (g1 > GG) g1 = GG;

    const float4* xp = (const float4*)(x + (size_t)(b * TT + n) * DD) + t4;
    float ax = 0.f, ay = 0.f, az = 0.f, aw = 0.f;
    #pragma unroll 4
    for (int g = g0; g < g1; ++g) {
        float4 v = xp[(size_t)g * NN * (DD / 4)];
        ax += v.x; ay += v.y; az += v.z; aw += v.w;
    }
    float4 r; r.x = ax; r.y = ay; r.z = az; r.w = aw;
    ((float4*)partial)[(size_t)(gs * BN + bn) * (DD / 4) + t4] = r;
}

// ---------------------------------------------------------------------------
// Kernel 2: reduce partials -> nodes.  grid = 56, block = 256 (one f4 each).
// ---------------------------------------------------------------------------
__global__ __launch_bounds__(256) void k_mean_reduce(
    const float* __restrict__ partial, float* __restrict__ nodes) {
    int i = blockIdx.x * 256 + threadIdx.x;   // 0 .. BN*256-1 (f4 units)
    const float4* p = (const float4*)partial;
    float4 a = p[i];
    #pragma unroll
    for (int gs = 1; gs < GSPLIT; ++gs) {
        float4 v = p[(size_t)gs * BN * (DD / 4) + i];
        a.x += v.x; a.y += v.y; a.z += v.z; a.w += v.w;
    }
    const float sc = 1.0f / (float)GG;
    a.x *= sc; a.y *= sc; a.z *= sc; a.w *= sc;
    ((float4*)nodes)[i] = a;
}

// ---------------------------------------------------------------------------
// Kernel 3/5: C[bn][d] = sum_k A[bn][k] * Wm[d][k]   (A: 56x1024, Wm: 1024x1024)
// grid = 1024 (one block per output column d), block = 256.
// Each thread owns k-range [4t, 4t+4); per-bn partial dot; butterfly reduce.
// ---------------------------------------------------------------------------
__global__ __launch_bounds__(256) void k_gemv(
    const float* __restrict__ A, const float* __restrict__ Wm,
    float* __restrict__ Cout) {
    int d = blockIdx.x;
    int t = threadIdx.x;
    int wave = t >> 6, lane = t & 63;

    float4 wv = ((const float4*)(Wm + (size_t)d * DD))[t];

    float acc[BN];
    const float4* ap = (const float4*)A + t;
    #pragma unroll
    for (int bn = 0; bn < BN; ++bn) {
        float4 av = ap[(size_t)bn * (DD / 4)];
        acc[bn] = av.x * wv.x + av.y * wv.y + av.z * wv.z + av.w * wv.w;
    }

    __shared__ float red[4][BN];
    #pragma unroll
    for (int bn = 0; bn < BN; ++bn) {
        float v = acc[bn];
        v += __shfl_xor(v, 1, 64);
        v += __shfl_xor(v, 2, 64);
        v += __shfl_xor(v, 4, 64);
        v += __shfl_xor(v, 8, 64);
        v += __shfl_xor(v, 16, 64);
        v += __shfl_xor(v, 32, 64);
        if (lane == 0) red[wave][bn] = v;
    }
    __syncthreads();
    if (t < BN) {
        float v = red[0][t] + red[1][t] + red[2][t] + red[3][t];
        Cout[(size_t)t * DD + d] = v;
    }
}

// ---------------------------------------------------------------------------
// Kernel 4: per-batch attention.  grid = 8, block = 256.
// f1[n]=h[n,:]@a1, f2[n]=h[n,:]@a2; e[i][j]=f1[i]+f2[j] masked; softmax;
// s[i,:] = sum_j alpha[i][j] h[j,:]
// ---------------------------------------------------------------------------
__global__ __launch_bounds__(256) void k_attn(
    const float* __restrict__ h, const float* __restrict__ a_w,
    float* __restrict__ s) {
    int b = blockIdx.x;
    __shared__ float hl[NN][DD];          // 28 KB
    __shared__ float f[2][NN];
    __shared__ float alpha[NN][NN];

    const float4* hp = (const float4*)(h + (size_t)b * NN * DD);
    float4* hl4 = (float4*)hl;
    for (int i = threadIdx.x; i < NN * (DD / 4); i += 256) hl4[i] = hp[i];
    __syncthreads();

    int wave = threadIdx.x >> 6, lane = threadIdx.x & 63;
    for (int task = wave; task < 2 * NN; task += 4) {
        int n = task % NN, sel = task / NN;
        const float* av = a_w + sel * DD;
        float sum = 0.f;
        for (int k = lane; k < DD; k += 64) sum += hl[n][k] * av[k];
        sum += __shfl_xor(sum, 1, 64);
        sum += __shfl_xor(sum, 2, 64);
        sum += __shfl_xor(sum, 4, 64);
        sum += __shfl_xor(sum, 8, 64);
        sum += __shfl_xor(sum, 16, 64);
        sum += __shfl_xor(sum, 32, 64);
        if (lane == 0) f[sel][n] = sum;
    }
    __syncthreads();

    if (threadIdx.x == 0) {
        const unsigned msk[NN] = {0x7Eu, 0x45u, 0x0Bu, 0x15u, 0x29u, 0x51u, 0x23u};
        #pragma unroll
        for (int i = 0; i < NN; ++i) {
            float m = -1e30f;
            #pragma unroll
            for (int j = 0; j < NN; ++j)
                if ((msk[i] >> j) & 1u) { float e = f[0][i] + f[1][j]; m = fmaxf(m, e); }
            float ssum = 0.f; float ex[NN];
            #pragma unroll
            for (int j = 0; j < NN; ++j) {
                ex[j] = ((msk[i] >> j) & 1u) ? expf(f[0][i] + f[1][j] - m) : 0.f;
                ssum += ex[j];
            }
            float inv = 1.0f / ssum;
            #pragma unroll
            for (int j = 0; j < NN; ++j) alpha[i][j] = ex[j] * inv;
        }
    }
    __syncthreads();

    float4* sp = (float4*)(s + (size_t)b * NN * DD);
    int t = threadIdx.x;    // one float4 per thread per i
    #pragma unroll
    for (int i = 0; i < NN; ++i) {
        float ax = 0.f, ay = 0.f, az = 0.f, aw = 0.f;
        #pragma unroll
        for (int j = 0; j < NN; ++j) {
            float a = alpha[i][j];
            float4 hv = hl4[j * (DD / 4) + t];
            ax += a * hv.x; ay += a * hv.y; az += a * hv.z; aw += a * hv.w;
        }
        float4 r; r.x = ax; r.y = ay; r.z = az; r.w = aw;
        sp[i * (DD / 4) + t] = r;
    }
}

// ---------------------------------------------------------------------------
// Kernel 6: out[b,t,d] = x[b,t,d] + on[b, t%7, d].  grid = (TT, BB), block=256.
// ---------------------------------------------------------------------------
__global__ __launch_bounds__(256) void k_final(
    const float* __restrict__ x, const float* __restrict__ on,
    float* __restrict__ out) {
    int t = blockIdx.x;
    int b = blockIdx.y;
    int n = t % NN;
    size_t row4 = (size_t)(b * TT + t) * (DD / 4) + threadIdx.x;
    size_t on4 = (size_t)(b * NN + n) * (DD / 4) + threadIdx.x;
    float4 xv = ((const float4*)x)[row4];
    float4 ov = ((const float4*)on)[on4];
    float4 r; r.x = xv.x + ov.x; r.y = xv.y + ov.y;
    r.z = xv.z + ov.z; r.w = xv.w + ov.w;
    ((float4*)out)[row4] = r;
}

// ---------------------------------------------------------------------------
extern "C" void kernel_launch(void* const* d_in, const int* in_sizes, int n_in,
                              void* d_out, int out_size, void* d_ws, size_t ws_size,
                              hipStream_t stream) {
    const float* x     = (const float*)d_in[0];
    const float* W     = (const float*)d_in[1];
    const float* a_w   = (const float*)d_in[2];
    const float* out_W = (const float*)d_in[3];
    float* out = (float*)d_out;
    float* ws  = (float*)d_ws;

    // ws layout (floats)
    float* partial = ws;                       // 8*56*1024 = 458752
    float* nodes   = ws + 458752;              // 56*1024
    float* h       = ws + 458752 + 57344;      // 56*1024
    float* s       = ws + 458752 + 2 * 57344;  // 56*1024
    float* on      = ws + 458752 + 3 * 57344;  // 56*1024

    k_mean_partial<<<dim3(GSPLIT, BN), 256, 0, stream>>>(x, partial);
    k_mean_reduce<<<dim3(BN), 256, 0, stream>>>(partial, nodes);
    k_gemv<<<dim3(DD), 256, 0, stream>>>(nodes, W, h);
    k_attn<<<dim3(BB), 256, 0, stream>>>(h, a_w, s);
    k_gemv<<<dim3(DD), 256, 0, stream>>>(s, out_W, on);
    k_final<<<dim3(TT, BB), 256, 0, stream>>>(x, on, out);
}

// Round 2
// 132.929 us; speedup vs baseline: 1.0940x; 1.0940x over previous
//
#include <hip/hip_runtime.h>
#include <math.h>

#define BB 8
#define TT 4095
#define DD 1024
#define NN 7
#define GG 585           // TT / NN
#define BN (BB * NN)     // 56
#define GSPLIT 16
#define GCHUNK 37        // ceil(585/16)

// ---------------------------------------------------------------------------
// Kernel 1: partial group-mean sums.  grid = (GSPLIT, BN), block = 256.
// ---------------------------------------------------------------------------
__global__ __launch_bounds__(256) void k_mean_partial(
    const float* __restrict__ x, float* __restrict__ partial) {
    int gs = blockIdx.x;             // 0..15
    int bn = blockIdx.y;             // 0..55
    int b = bn / NN, n = bn % NN;
    int t4 = threadIdx.x;            // float4 index within row, 0..255
    int g0 = gs * GCHUNK;
    int g1 = g0 + GCHUNK; if (g1 > GG) g1 = GG;

    const float4* xp = (const float4*)(x + (size_t)(b * TT + n) * DD) + t4;
    float ax = 0.f, ay = 0.f, az = 0.f, aw = 0.f;
    #pragma unroll 4
    for (int g = g0; g < g1; ++g) {
        float4 v = xp[(size_t)g * NN * (DD / 4)];
        ax += v.x; ay += v.y; az += v.z; aw += v.w;
    }
    float4 r; r.x = ax; r.y = ay; r.z = az; r.w = aw;
    ((float4*)partial)[(size_t)(gs * BN + bn) * (DD / 4) + t4] = r;
}

// ---------------------------------------------------------------------------
// Kernel 2: reduce partials -> nodes.  grid = 56, block = 256 (one f4 each).
// ---------------------------------------------------------------------------
__global__ __launch_bounds__(256) void k_mean_reduce(
    const float* __restrict__ partial, float* __restrict__ nodes) {
    int i = blockIdx.x * 256 + threadIdx.x;   // 0 .. BN*256-1 (f4 units)
    const float4* p = (const float4*)partial;
    float4 a = p[i];
    #pragma unroll
    for (int gs = 1; gs < GSPLIT; ++gs) {
        float4 v = p[(size_t)gs * BN * (DD / 4) + i];
        a.x += v.x; a.y += v.y; a.z += v.z; a.w += v.w;
    }
    const float sc = 1.0f / (float)GG;
    a.x *= sc; a.y *= sc; a.z *= sc; a.w *= sc;
    ((float4*)nodes)[i] = a;
}

// ---------------------------------------------------------------------------
// Kernel 3/5: C[bn][d] = sum_k A[bn][k] * Wm[d][k]  (A: 56x1024, Wm: 1024x1024)
// grid = 1024 (one block per output column d), block = 256 (4 waves).
// Wave w owns rows [14w, 14w+14); lanes span full K (4 x float4 each).
// ---------------------------------------------------------------------------
__global__ __launch_bounds__(256) void k_gemv(
    const float* __restrict__ A, const float* __restrict__ Wm,
    float* __restrict__ Cout) {
    int d = blockIdx.x;
    int t = threadIdx.x;
    int wave = t >> 6, lane = t & 63;

    const float4* wp = (const float4*)(Wm + (size_t)d * DD);
    float4 w0 = wp[lane];
    float4 w1 = wp[lane + 64];
    float4 w2 = wp[lane + 128];
    float4 w3 = wp[lane + 192];

    const float4* ap = (const float4*)A + (size_t)(wave * 14) * (DD / 4);
    float acc[14];
    #pragma unroll
    for (int i = 0; i < 14; ++i) {
        const float4* ar = ap + (size_t)i * (DD / 4);
        float4 a0 = ar[lane];
        float4 a1 = ar[lane + 64];
        float4 a2 = ar[lane + 128];
        float4 a3 = ar[lane + 192];
        float v = a0.x * w0.x + a0.y * w0.y + a0.z * w0.z + a0.w * w0.w;
        v += a1.x * w1.x + a1.y * w1.y + a1.z * w1.z + a1.w * w1.w;
        v += a2.x * w2.x + a2.y * w2.y + a2.z * w2.z + a2.w * w2.w;
        v += a3.x * w3.x + a3.y * w3.y + a3.z * w3.z + a3.w * w3.w;
        acc[i] = v;
    }

    #pragma unroll
    for (int i = 0; i < 14; ++i) {
        float v = acc[i];
        v += __shfl_xor(v, 1, 64);
        v += __shfl_xor(v, 2, 64);
        v += __shfl_xor(v, 4, 64);
        v += __shfl_xor(v, 8, 64);
        v += __shfl_xor(v, 16, 64);
        v += __shfl_xor(v, 32, 64);
        if (lane == 0) Cout[(size_t)(wave * 14 + i) * DD + d] = v;
    }
}

// ---------------------------------------------------------------------------
// Kernel 4: per-batch attention.  grid = 8, block = 256.
// ---------------------------------------------------------------------------
__global__ __launch_bounds__(256) void k_attn(
    const float* __restrict__ h, const float* __restrict__ a_w,
    float* __restrict__ s) {
    int b = blockIdx.x;
    __shared__ float hl[NN][DD];          // 28 KB
    __shared__ float f[2][NN];
    __shared__ float alpha[NN][NN];

    const float4* hp = (const float4*)(h + (size_t)b * NN * DD);
    float4* hl4 = (float4*)hl;
    for (int i = threadIdx.x; i < NN * (DD / 4); i += 256) hl4[i] = hp[i];
    __syncthreads();

    int wave = threadIdx.x >> 6, lane = threadIdx.x & 63;
    for (int task = wave; task < 2 * NN; task += 4) {
        int n = task % NN, sel = task / NN;
        const float* av = a_w + sel * DD;
        float sum = 0.f;
        for (int k = lane; k < DD; k += 64) sum += hl[n][k] * av[k];
        sum += __shfl_xor(sum, 1, 64);
        sum += __shfl_xor(sum, 2, 64);
        sum += __shfl_xor(sum, 4, 64);
        sum += __shfl_xor(sum, 8, 64);
        sum += __shfl_xor(sum, 16, 64);
        sum += __shfl_xor(sum, 32, 64);
        if (lane == 0) f[sel][n] = sum;
    }
    __syncthreads();

    if (threadIdx.x == 0) {
        const unsigned msk[NN] = {0x7Eu, 0x45u, 0x0Bu, 0x15u, 0x29u, 0x51u, 0x23u};
        #pragma unroll
        for (int i = 0; i < NN; ++i) {
            float m = -1e30f;
            #pragma unroll
            for (int j = 0; j < NN; ++j)
                if ((msk[i] >> j) & 1u) { float e = f[0][i] + f[1][j]; m = fmaxf(m, e); }
            float ssum = 0.f; float ex[NN];
            #pragma unroll
            for (int j = 0; j < NN; ++j) {
                ex[j] = ((msk[i] >> j) & 1u) ? expf(f[0][i] + f[1][j] - m) : 0.f;
                ssum += ex[j];
            }
            float inv = 1.0f / ssum;
            #pragma unroll
            for (int j = 0; j < NN; ++j) alpha[i][j] = ex[j] * inv;
        }
    }
    __syncthreads();

    float4* sp = (float4*)(s + (size_t)b * NN * DD);
    int t = threadIdx.x;    // one float4 per thread per i
    #pragma unroll
    for (int i = 0; i < NN; ++i) {
        float ax = 0.f, ay = 0.f, az = 0.f, aw = 0.f;
        #pragma unroll
        for (int j = 0; j < NN; ++j) {
            float a = alpha[i][j];
            float4 hv = hl4[j * (DD / 4) + t];
            ax += a * hv.x; ay += a * hv.y; az += a * hv.z; aw += a * hv.w;
        }
        float4 r; r.x = ax; r.y = ay; r.z = az; r.w = aw;
        sp[i * (DD / 4) + t] = r;
    }
}

// ---------------------------------------------------------------------------
// Kernel 6: out[b,t,d] = x[b,t,d] + on[b, t%7, d].  grid = (TT, BB), block=256.
// ---------------------------------------------------------------------------
__global__ __launch_bounds__(256) void k_final(
    const float* __restrict__ x, const float* __restrict__ on,
    float* __restrict__ out) {
    int t = blockIdx.x;
    int b = blockIdx.y;
    int n = t % NN;
    size_t row4 = (size_t)(b * TT + t) * (DD / 4) + threadIdx.x;
    size_t on4 = (size_t)(b * NN + n) * (DD / 4) + threadIdx.x;
    float4 xv = ((const float4*)x)[row4];
    float4 ov = ((const float4*)on)[on4];
    float4 r; r.x = xv.x + ov.x; r.y = xv.y + ov.y;
    r.z = xv.z + ov.z; r.w = xv.w + ov.w;
    ((float4*)out)[row4] = r;
}

// ---------------------------------------------------------------------------
extern "C" void kernel_launch(void* const* d_in, const int* in_sizes, int n_in,
                              void* d_out, int out_size, void* d_ws, size_t ws_size,
                              hipStream_t stream) {
    const float* x     = (const float*)d_in[0];
    const float* W     = (const float*)d_in[1];
    const float* a_w   = (const float*)d_in[2];
    const float* out_W = (const float*)d_in[3];
    float* out = (float*)d_out;
    float* ws  = (float*)d_ws;

    // ws layout (floats)
    float* partial = ws;                            // 16*56*1024 = 917504
    float* nodes   = ws + 917504;                   // 56*1024
    float* h       = ws + 917504 + 57344;           // 56*1024
    float* s       = ws + 917504 + 2 * 57344;       // 56*1024
    float* on      = ws + 917504 + 3 * 57344;       // 56*1024

    k_mean_partial<<<dim3(GSPLIT, BN), 256, 0, stream>>>(x, partial);
    k_mean_reduce<<<dim3(BN), 256, 0, stream>>>(partial, nodes);
    k_gemv<<<dim3(DD), 256, 0, stream>>>(nodes, W, h);
    k_attn<<<dim3(BB), 256, 0, stream>>>(h, a_w, s);
    k_gemv<<<dim3(DD), 256, 0, stream>>>(s, out_W, on);
    k_final<<<dim3(TT, BB), 256, 0, stream>>>(x, on, out);
}

// Round 4
// 120.050 us; speedup vs baseline: 1.2113x; 1.1073x over previous
//
#include <hip/hip_runtime.h>
#include <math.h>

#define BB 8
#define TT 4095
#define DD 1024
#define NN 7
#define GG 585           // TT / NN
#define BN (BB * NN)     // 56
#define GSPLIT 16
#define GCHUNK 37        // ceil(585/16)
#define GD 4             // output columns per gemv block

typedef float nfloat4 __attribute__((ext_vector_type(4)));

// ---------------------------------------------------------------------------
// Kernel 1: partial group-mean sums.  grid = (GSPLIT, BN), block = 256.
// ---------------------------------------------------------------------------
__global__ __launch_bounds__(256) void k_mean_partial(
    const float* __restrict__ x, float* __restrict__ partial) {
    int gs = blockIdx.x;             // 0..15
    int bn = blockIdx.y;             // 0..55
    int b = bn / NN, n = bn % NN;
    int t4 = threadIdx.x;            // float4 index within row, 0..255
    int g0 = gs * GCHUNK;
    int g1 = g0 + GCHUNK; if (g1 > GG) g1 = GG;

    const float4* xp = (const float4*)(x + (size_t)(b * TT + n) * DD) + t4;
    float ax = 0.f, ay = 0.f, az = 0.f, aw = 0.f;
    #pragma unroll 4
    for (int g = g0; g < g1; ++g) {
        float4 v = xp[(size_t)g * NN * (DD / 4)];
        ax += v.x; ay += v.y; az += v.z; aw += v.w;
    }
    float4 r; r.x = ax; r.y = ay; r.z = az; r.w = aw;
    ((float4*)partial)[(size_t)(gs * BN + bn) * (DD / 4) + t4] = r;
}

// ---------------------------------------------------------------------------
// Kernel 2: reduce partials -> nodes.  grid = 56, block = 256 (one f4 each).
// ---------------------------------------------------------------------------
__global__ __launch_bounds__(256) void k_mean_reduce(
    const float* __restrict__ partial, float* __restrict__ nodes) {
    int i = blockIdx.x * 256 + threadIdx.x;   // 0 .. BN*256-1 (f4 units)
    const float4* p = (const float4*)partial;
    float4 a = p[i];
    #pragma unroll
    for (int gs = 1; gs < GSPLIT; ++gs) {
        float4 v = p[(size_t)gs * BN * (DD / 4) + i];
        a.x += v.x; a.y += v.y; a.z += v.z; a.w += v.w;
    }
    const float sc = 1.0f / (float)GG;
    a.x *= sc; a.y *= sc; a.z *= sc; a.w *= sc;
    ((float4*)nodes)[i] = a;
}

// ---------------------------------------------------------------------------
// Kernel 3/5: C[bn][d] = sum_k A[bn][k] * Wm[d][k]  (A: 56x1024, Wm: 1024x1024)
// grid = DD/GD = 256 blocks; each block computes GD=4 output columns.
// Wave w owns rows [14w, 14w+14); lanes span full K (4 x float4 each).
// ---------------------------------------------------------------------------
__global__ __launch_bounds__(256) void k_gemv(
    const float* __restrict__ A, const float* __restrict__ Wm,
    float* __restrict__ Cout) {
    int d0 = blockIdx.x * GD;
    int t = threadIdx.x;
    int wave = t >> 6, lane = t & 63;

    float4 wv[GD][4];
    #pragma unroll
    for (int dd = 0; dd < GD; ++dd) {
        const float4* wp = (const float4*)(Wm + (size_t)(d0 + dd) * DD);
        #pragma unroll
        for (int kk = 0; kk < 4; ++kk) wv[dd][kk] = wp[lane + 64 * kk];
    }

    const float4* ap = (const float4*)A + (size_t)(wave * 14) * (DD / 4);
    float acc[14][GD];
    #pragma unroll
    for (int i = 0; i < 14; ++i) {
        const float4* ar = ap + (size_t)i * (DD / 4);
        float4 a0 = ar[lane];
        float4 a1 = ar[lane + 64];
        float4 a2 = ar[lane + 128];
        float4 a3 = ar[lane + 192];
        #pragma unroll
        for (int dd = 0; dd < GD; ++dd) {
            float v = a0.x * wv[dd][0].x + a0.y * wv[dd][0].y +
                      a0.z * wv[dd][0].z + a0.w * wv[dd][0].w;
            v += a1.x * wv[dd][1].x + a1.y * wv[dd][1].y +
                 a1.z * wv[dd][1].z + a1.w * wv[dd][1].w;
            v += a2.x * wv[dd][2].x + a2.y * wv[dd][2].y +
                 a2.z * wv[dd][2].z + a2.w * wv[dd][2].w;
            v += a3.x * wv[dd][3].x + a3.y * wv[dd][3].y +
                 a3.z * wv[dd][3].z + a3.w * wv[dd][3].w;
            acc[i][dd] = v;
        }
    }

    #pragma unroll
    for (int i = 0; i < 14; ++i) {
        #pragma unroll
        for (int dd = 0; dd < GD; ++dd) {
            float v = acc[i][dd];
            v += __shfl_xor(v, 1, 64);
            v += __shfl_xor(v, 2, 64);
            v += __shfl_xor(v, 4, 64);
            v += __shfl_xor(v, 8, 64);
            v += __shfl_xor(v, 16, 64);
            v += __shfl_xor(v, 32, 64);
            if (lane == 0) Cout[(size_t)(wave * 14 + i) * DD + d0 + dd] = v;
        }
    }
}

// ---------------------------------------------------------------------------
// Kernel 4: per-batch attention.  grid = 8, block = 256.
// ---------------------------------------------------------------------------
__global__ __launch_bounds__(256) void k_attn(
    const float* __restrict__ h, const float* __restrict__ a_w,
    float* __restrict__ s) {
    int b = blockIdx.x;
    __shared__ float hl[NN][DD];          // 28 KB
    __shared__ float f[2][NN];
    __shared__ float alpha[NN][NN];

    const float4* hp = (const float4*)(h + (size_t)b * NN * DD);
    float4* hl4 = (float4*)hl;
    for (int i = threadIdx.x; i < NN * (DD / 4); i += 256) hl4[i] = hp[i];
    __syncthreads();

    int wave = threadIdx.x >> 6, lane = threadIdx.x & 63;
    for (int task = wave; task < 2 * NN; task += 4) {
        int n = task % NN, sel = task / NN;
        const float* av = a_w + sel * DD;
        float sum = 0.f;
        for (int k = lane; k < DD; k += 64) sum += hl[n][k] * av[k];
        sum += __shfl_xor(sum, 1, 64);
        sum += __shfl_xor(sum, 2, 64);
        sum += __shfl_xor(sum, 4, 64);
        sum += __shfl_xor(sum, 8, 64);
        sum += __shfl_xor(sum, 16, 64);
        sum += __shfl_xor(sum, 32, 64);
        if (lane == 0) f[sel][n] = sum;
    }
    __syncthreads();

    if (threadIdx.x == 0) {
        const unsigned msk[NN] = {0x7Eu, 0x45u, 0x0Bu, 0x15u, 0x29u, 0x51u, 0x23u};
        #pragma unroll
        for (int i = 0; i < NN; ++i) {
            float m = -1e30f;
            #pragma unroll
            for (int j = 0; j < NN; ++j)
                if ((msk[i] >> j) & 1u) { float e = f[0][i] + f[1][j]; m = fmaxf(m, e); }
            float ssum = 0.f; float ex[NN];
            #pragma unroll
            for (int j = 0; j < NN; ++j) {
                ex[j] = ((msk[i] >> j) & 1u) ? expf(f[0][i] + f[1][j] - m) : 0.f;
                ssum += ex[j];
            }
            float inv = 1.0f / ssum;
            #pragma unroll
            for (int j = 0; j < NN; ++j) alpha[i][j] = ex[j] * inv;
        }
    }
    __syncthreads();

    float4* sp = (float4*)(s + (size_t)b * NN * DD);
    int t = threadIdx.x;    // one float4 per thread per i
    #pragma unroll
    for (int i = 0; i < NN; ++i) {
        float ax = 0.f, ay = 0.f, az = 0.f, aw = 0.f;
        #pragma unroll
        for (int j = 0; j < NN; ++j) {
            float a = alpha[i][j];
            float4 hv = hl4[j * (DD / 4) + t];
            ax += a * hv.x; ay += a * hv.y; az += a * hv.z; aw += a * hv.w;
        }
        float4 r; r.x = ax; r.y = ay; r.z = az; r.w = aw;
        sp[i * (DD / 4) + t] = r;
    }
}

// ---------------------------------------------------------------------------
// Kernel 6: out[b,t,d] = x[b,t,d] + on[b, t%7, d].  grid = (TT, BB), block=256.
// Non-temporal stores (nt): out is write-once; keep it from evicting x in L3
// (x = 134 MB < 256 MB L3) so both x-reads hit L3 across replays.
// ---------------------------------------------------------------------------
__global__ __launch_bounds__(256) void k_final(
    const float* __restrict__ x, const float* __restrict__ on,
    float* __restrict__ out) {
    int t = blockIdx.x;
    int b = blockIdx.y;
    int n = t % NN;
    size_t row4 = (size_t)(b * TT + t) * (DD / 4) + threadIdx.x;
    size_t on4 = (size_t)(b * NN + n) * (DD / 4) + threadIdx.x;
    float4 xv = ((const float4*)x)[row4];
    float4 ov = ((const float4*)on)[on4];
    nfloat4 r;
    r.x = xv.x + ov.x; r.y = xv.y + ov.y;
    r.z = xv.z + ov.z; r.w = xv.w + ov.w;
    __builtin_nontemporal_store(r, (nfloat4*)out + row4);
}

// ---------------------------------------------------------------------------
extern "C" void kernel_launch(void* const* d_in, const int* in_sizes, int n_in,
                              void* d_out, int out_size, void* d_ws, size_t ws_size,
                              hipStream_t stream) {
    const float* x     = (const float*)d_in[0];
    const float* W     = (const float*)d_in[1];
    const float* a_w   = (const float*)d_in[2];
    const float* out_W = (const float*)d_in[3];
    float* out = (float*)d_out;
    float* ws  = (float*)d_ws;

    // ws layout (floats)
    float* partial = ws;                            // 16*56*1024 = 917504
    float* nodes   = ws + 917504;                   // 56*1024
    float* h       = ws + 917504 + 57344;           // 56*1024
    float* s       = ws + 917504 + 2 * 57344;       // 56*1024
    float* on      = ws + 917504 + 3 * 57344;       // 56*1024

    k_mean_partial<<<dim3(GSPLIT, BN), 256, 0, stream>>>(x, partial);
    k_mean_reduce<<<dim3(BN), 256, 0, stream>>>(partial, nodes);
    k_gemv<<<dim3(DD / GD), 256, 0, stream>>>(nodes, W, h);
    k_attn<<<dim3(BB), 256, 0, stream>>>(h, a_w, s);
    k_gemv<<<dim3(DD / GD), 256, 0, stream>>>(s, out_W, on);
    k_final<<<dim3(TT, BB), 256, 0, stream>>>(x, on, out);
}